// Round 8
// baseline (796.549 us; speedup 1.0000x reference)
//
#include <hip/hip_runtime.h>

#define BB 64
#define TT 1024
#define DD 256
#define HH 256
#define CH 8             // timesteps per LDS chunk
#define NCH (TT / CH)    // 128 chunks

typedef float vf4 __attribute__((ext_vector_type(4)));
typedef float vf2 __attribute__((ext_vector_type(2)));
struct alignas(16) v2x2 { vf2 lo, hi; };   // one 16-B load, two pk-operands

#define LD4(p) (*(const vf4*)(p))
#define LDW(p) (*(const v2x2*)(p))

// tanh(x) = 1 - 2/(e^{2x}+1); saturates correctly for large |x|.
__device__ __forceinline__ float fast_tanh(float x) {
    float e = __expf(2.0f * x);
    return 1.0f - 2.0f / (e + 1.0f);
}

// Strict-VGPR packed FMA/MUL via inline asm. R9 proved gfx950 VALU cannot
// source AGPRs (assembler rejects "v_fma_f32 v,a,v,v"), so the allocator's
// habit of parking loop-invariant weights in AGPRs costs one v_accvgpr_read
// per weight per use. These asm ops put a hard VGPR requirement at EVERY
// use site: the allocator must either keep weights arch-VGPR-resident
// (copies vanish; 256-reg budget at waves_per_eu(2,2) fits) or copy per
// use (status quo, no worse). v_pk_* = 2 fp32 lanes/inst, exact.
#define APKMUL(acc, ww, hh) \
    asm("v_pk_mul_f32 %0, %1, %2" : "=v"(acc) : "v"(ww), "v"(hh))
#define APKFMA(acc, ww, hh) \
    asm("v_pk_fma_f32 %0, %1, %2, %0" : "+v"(acc) : "v"(ww), "v"(hh))

// dst = src + dpp_shuffle(src). VALU-pipe cross-lane (no LDS traffic).
// CTRL: 0xB1 quad_perm xor1, 0x4E quad_perm xor2, 0x124 row_ror:4, 0x128 row_ror:8.
#define DPPADD(dst, src, CTRL) {                                                   \
    int _di = __builtin_amdgcn_update_dpp(0, __float_as_int(src), CTRL, 0xF, 0xF, true); \
    dst = (src) + __int_as_float(_di); }

// NOTE: macro params must NOT be named x/y/z/w (component-accessor capture).
#define FMR(rr, bb, ss)                   \
    rr.x = fmaf((ss), (bb).x, rr.x);      \
    rr.y = fmaf((ss), (bb).y, rr.y);      \
    rr.z = fmaf((ss), (bb).z, rr.z);      \
    rr.w = fmaf((ss), (bb).w, rr.w)

// ---------------------------------------------------------------------------
// Phase 1 (unchanged, ~160 us): xp = x * W_ih^T + b_ih, tiled GEMM.
// ---------------------------------------------------------------------------
#define BKb 32
#define LDP 132

__global__ __attribute__((amdgpu_flat_work_group_size(256, 256),
                          amdgpu_waves_per_eu(4, 4)))
void xproj_kernel(const float* __restrict__ x, const float* __restrict__ W_ih,
                  const float* __restrict__ b_ih, float* __restrict__ xp)
{
    __shared__ float As[BKb][LDP];
    __shared__ float Bs[BKb][LDP];

    const int tid = threadIdx.x;
    const int nb = blockIdx.x & 1;
    const int mb = blockIdx.x >> 1;
    const int m0 = mb * 128;
    const int n0 = nb * 128;

    const int sr = tid >> 3;
    const int sk = (tid & 7) * 4;

    const int tx = tid & 15;
    const int ty = tid >> 4;
    const int ma = ty * 4, mh = 64 + ty * 4;
    const int na = tx * 4, nh = 64 + tx * 4;

    vf4 ra0 = 0, ra1 = 0, ra2 = 0, ra3 = 0, ra4 = 0, ra5 = 0, ra6 = 0, ra7 = 0;
    vf4 rb0 = 0, rb1 = 0, rb2 = 0, rb3 = 0, rb4 = 0, rb5 = 0, rb6 = 0, rb7 = 0;

    for (int k0 = 0; k0 < DD; k0 += BKb) {
        #pragma unroll
        for (int g = 0; g < 4; ++g) {
            const int r = sr + g * 32;
            const vf4 v = LD4(x + (size_t)(m0 + r) * DD + k0 + sk);
            As[sk + 0][r] = v.x; As[sk + 1][r] = v.y;
            As[sk + 2][r] = v.z; As[sk + 3][r] = v.w;
        }
        #pragma unroll
        for (int g = 0; g < 4; ++g) {
            const int n = sr + g * 32;
            const vf4 v = LD4(W_ih + (size_t)(n0 + n) * DD + k0 + sk);
            Bs[sk + 0][n] = v.x; Bs[sk + 1][n] = v.y;
            Bs[sk + 2][n] = v.z; Bs[sk + 3][n] = v.w;
        }
        __syncthreads();

        #pragma unroll
        for (int kk = 0; kk < BKb; ++kk) {
            const vf4 alo = LD4(&As[kk][ma]);
            const vf4 ahi = LD4(&As[kk][mh]);
            const vf4 bl  = LD4(&Bs[kk][na]);
            const vf4 bh  = LD4(&Bs[kk][nh]);
            FMR(ra0, bl, alo.x); FMR(rb0, bh, alo.x);
            FMR(ra1, bl, alo.y); FMR(rb1, bh, alo.y);
            FMR(ra2, bl, alo.z); FMR(rb2, bh, alo.z);
            FMR(ra3, bl, alo.w); FMR(rb3, bh, alo.w);
            FMR(ra4, bl, ahi.x); FMR(rb4, bh, ahi.x);
            FMR(ra5, bl, ahi.y); FMR(rb5, bh, ahi.y);
            FMR(ra6, bl, ahi.z); FMR(rb6, bh, ahi.z);
            FMR(ra7, bl, ahi.w); FMR(rb7, bh, ahi.w);
        }
        __syncthreads();
    }

    const vf4 bia = LD4(b_ih + n0 + na);
    const vf4 bib = LD4(b_ih + n0 + nh);

    #define STORE_ROW(m, rA, rB)                                   \
        {                                                          \
            float* outp = xp + (size_t)(m0 + (m)) * HH + n0;       \
            *(vf4*)(outp + na) = rA + bia;                         \
            *(vf4*)(outp + nh) = rB + bib;                         \
        }
    STORE_ROW(ma + 0, ra0, rb0); STORE_ROW(ma + 1, ra1, rb1);
    STORE_ROW(ma + 2, ra2, rb2); STORE_ROW(ma + 3, ra3, rb3);
    STORE_ROW(mh + 0, ra4, rb4); STORE_ROW(mh + 1, ra5, rb5);
    STORE_ROW(mh + 2, ra6, rb6); STORE_ROW(mh + 3, ra7, rb7);
    #undef STORE_ROW
}

// ---------------------------------------------------------------------------
// Phase 2: recurrence, one WG per batch (64 WGs, 512 threads).
// G=8 outputs/lane x L=16 k-elems/lane; chunk-staged xp/out through LDS.
// Identical to the 617us R8 kernel EXCEPT: the inner dot product uses
// inline-asm v_pk_mul/ fma_f32 with strict "v" constraints — a hard VGPR
// requirement at every weight USE site (see APKFMA comment). Single-variable
// A/B against R8: if the allocator flips to arch-VGPR weight residency,
// the ~110 v_accvgpr_read copies/step disappear (~30% of step issue).
// ---------------------------------------------------------------------------
__global__ __attribute__((amdgpu_flat_work_group_size(512, 512),
                          amdgpu_waves_per_eu(2, 2)))
void rnn_kernel(const float* __restrict__ W_hh, const float* __restrict__ b_hh,
                const float* __restrict__ xpin, float* __restrict__ hout)
{
    const int tid = threadIdx.x;
    const int jg = tid >> 4;          // 0..31: group of 8 outputs
    const int c  = tid & 15;          // 0..15: k-chunk (16 floats)
    const int j0 = jg * 8;
    const int jmine = j0 + (c & 7);   // the output this lane finalizes (writers: c<8)
    const int b = blockIdx.x;

    __shared__ float hbuf[2][16 * 20];     // h[k] at word (k>>4)*20 + (k&15)
    __shared__ float xchk[2][CH * HH];     // xp chunk double-buffer (2 x 8 KB)
    __shared__ float obuf[2][CH * HH];     // output staging double-buffer (2 x 8 KB)

    // Weights: 8 rows (j0..j0+7) x 16 cols (c*16..c*16+15) = 128 floats/lane.
    v2x2 w[8][4];
    #pragma unroll
    for (int r = 0; r < 8; ++r) {
        const float* wr = W_hh + (size_t)(j0 + r) * HH + c * 16;
        w[r][0] = LDW(wr + 0);  w[r][1] = LDW(wr + 4);
        w[r][2] = LDW(wr + 8);  w[r][3] = LDW(wr + 12);
    }
    const float bias = b_hh[jmine];

    // Pin weights ONCE (opaque redefinition => loads cannot be
    // rematerialized/sunk into the loop).
    asm volatile("" : "+v"(w[0][0].lo), "+v"(w[0][0].hi), "+v"(w[0][1].lo), "+v"(w[0][1].hi),
                      "+v"(w[0][2].lo), "+v"(w[0][2].hi), "+v"(w[0][3].lo), "+v"(w[0][3].hi),
                      "+v"(w[1][0].lo), "+v"(w[1][0].hi), "+v"(w[1][1].lo), "+v"(w[1][1].hi),
                      "+v"(w[1][2].lo), "+v"(w[1][2].hi), "+v"(w[1][3].lo), "+v"(w[1][3].hi));
    asm volatile("" : "+v"(w[2][0].lo), "+v"(w[2][0].hi), "+v"(w[2][1].lo), "+v"(w[2][1].hi),
                      "+v"(w[2][2].lo), "+v"(w[2][2].hi), "+v"(w[2][3].lo), "+v"(w[2][3].hi),
                      "+v"(w[3][0].lo), "+v"(w[3][0].hi), "+v"(w[3][1].lo), "+v"(w[3][1].hi),
                      "+v"(w[3][2].lo), "+v"(w[3][2].hi), "+v"(w[3][3].lo), "+v"(w[3][3].hi));
    asm volatile("" : "+v"(w[4][0].lo), "+v"(w[4][0].hi), "+v"(w[4][1].lo), "+v"(w[4][1].hi),
                      "+v"(w[4][2].lo), "+v"(w[4][2].hi), "+v"(w[4][3].lo), "+v"(w[4][3].hi),
                      "+v"(w[5][0].lo), "+v"(w[5][0].hi), "+v"(w[5][1].lo), "+v"(w[5][1].hi),
                      "+v"(w[5][2].lo), "+v"(w[5][2].hi), "+v"(w[5][3].lo), "+v"(w[5][3].hi));
    asm volatile("" : "+v"(w[6][0].lo), "+v"(w[6][0].hi), "+v"(w[6][1].lo), "+v"(w[6][1].hi),
                      "+v"(w[6][2].lo), "+v"(w[6][2].hi), "+v"(w[6][3].lo), "+v"(w[6][3].hi),
                      "+v"(w[7][0].lo), "+v"(w[7][0].hi), "+v"(w[7][1].lo), "+v"(w[7][1].hi),
                      "+v"(w[7][2].lo), "+v"(w[7][2].hi), "+v"(w[7][3].lo), "+v"(w[7][3].hi));

    const float* xbase = xpin + (size_t)b * TT * HH;
    float*       obase = hout + (size_t)b * TT * HH;
    const int haddr = ((jmine >> 4) * 20) + (jmine & 15);   // LDS slot for jmine

    // ---- prologue: chunk 0 into LDS, chunk 1 into registers (in flight) ----
    vf4 rpf = LD4(xbase + tid * 4);               // chunk 0 (2048 floats, 4/thread)
    if (tid < 320) hbuf[0][tid] = 0.0f;           // h_0 = 0 (pads incl.)
    *(vf4*)&xchk[0][tid * 4] = rpf;               // (compiler inserts vmcnt wait)
    rpf = LD4(xbase + CH * HH + tid * 4);         // chunk 1, stays in flight
    __syncthreads();

    for (int ci = 0; ci < NCH; ++ci) {
        const int cb = ci & 1;

        const float* xc = &xchk[cb][0];
        float*       ob = &obuf[cb][0];

        // unroll 2: hbuf[s&1] parity compile-time, pressure spike avoided.
        #pragma unroll 2
        for (int s = 0; s < CH; ++s) {
            // xp for this step: LDS read.
            const float xpb = xc[s * HH + jmine] + bias;

            const float* hc = &hbuf[s & 1][c * 20];
            const v2x2 h0 = LDW(hc + 0), h1 = LDW(hc + 4),
                       h2 = LDW(hc + 8), h3 = LDW(hc + 12);

            vf2 a0, a1, a2, a3, a4, a5, a6, a7;
            APKMUL(a0, w[0][0].lo, h0.lo); APKMUL(a1, w[1][0].lo, h0.lo);
            APKMUL(a2, w[2][0].lo, h0.lo); APKMUL(a3, w[3][0].lo, h0.lo);
            APKMUL(a4, w[4][0].lo, h0.lo); APKMUL(a5, w[5][0].lo, h0.lo);
            APKMUL(a6, w[6][0].lo, h0.lo); APKMUL(a7, w[7][0].lo, h0.lo);
            APKFMA(a0, w[0][0].hi, h0.hi); APKFMA(a1, w[1][0].hi, h0.hi);
            APKFMA(a2, w[2][0].hi, h0.hi); APKFMA(a3, w[3][0].hi, h0.hi);
            APKFMA(a4, w[4][0].hi, h0.hi); APKFMA(a5, w[5][0].hi, h0.hi);
            APKFMA(a6, w[6][0].hi, h0.hi); APKFMA(a7, w[7][0].hi, h0.hi);
            APKFMA(a0, w[0][1].lo, h1.lo); APKFMA(a1, w[1][1].lo, h1.lo);
            APKFMA(a2, w[2][1].lo, h1.lo); APKFMA(a3, w[3][1].lo, h1.lo);
            APKFMA(a4, w[4][1].lo, h1.lo); APKFMA(a5, w[5][1].lo, h1.lo);
            APKFMA(a6, w[6][1].lo, h1.lo); APKFMA(a7, w[7][1].lo, h1.lo);
            APKFMA(a0, w[0][1].hi, h1.hi); APKFMA(a1, w[1][1].hi, h1.hi);
            APKFMA(a2, w[2][1].hi, h1.hi); APKFMA(a3, w[3][1].hi, h1.hi);
            APKFMA(a4, w[4][1].hi, h1.hi); APKFMA(a5, w[5][1].hi, h1.hi);
            APKFMA(a6, w[6][1].hi, h1.hi); APKFMA(a7, w[7][1].hi, h1.hi);
            APKFMA(a0, w[0][2].lo, h2.lo); APKFMA(a1, w[1][2].lo, h2.lo);
            APKFMA(a2, w[2][2].lo, h2.lo); APKFMA(a3, w[3][2].lo, h2.lo);
            APKFMA(a4, w[4][2].lo, h2.lo); APKFMA(a5, w[5][2].lo, h2.lo);
            APKFMA(a6, w[6][2].lo, h2.lo); APKFMA(a7, w[7][2].lo, h2.lo);
            APKFMA(a0, w[0][2].hi, h2.hi); APKFMA(a1, w[1][2].hi, h2.hi);
            APKFMA(a2, w[2][2].hi, h2.hi); APKFMA(a3, w[3][2].hi, h2.hi);
            APKFMA(a4, w[4][2].hi, h2.hi); APKFMA(a5, w[5][2].hi, h2.hi);
            APKFMA(a6, w[6][2].hi, h2.hi); APKFMA(a7, w[7][2].hi, h2.hi);
            APKFMA(a0, w[0][3].lo, h3.lo); APKFMA(a1, w[1][3].lo, h3.lo);
            APKFMA(a2, w[2][3].lo, h3.lo); APKFMA(a3, w[3][3].lo, h3.lo);
            APKFMA(a4, w[4][3].lo, h3.lo); APKFMA(a5, w[5][3].lo, h3.lo);
            APKFMA(a6, w[6][3].lo, h3.lo); APKFMA(a7, w[7][3].lo, h3.lo);
            APKFMA(a0, w[0][3].hi, h3.hi); APKFMA(a1, w[1][3].hi, h3.hi);
            APKFMA(a2, w[2][3].hi, h3.hi); APKFMA(a3, w[3][3].hi, h3.hi);
            APKFMA(a4, w[4][3].hi, h3.hi); APKFMA(a5, w[5][3].hi, h3.hi);
            APKFMA(a6, w[6][3].hi, h3.hi); APKFMA(a7, w[7][3].hi, h3.hi);

            const float s0 = a0.x + a0.y, s1 = a1.x + a1.y,
                        s2 = a2.x + a2.y, s3 = a3.x + a3.y,
                        s4 = a4.x + a4.y, s5 = a5.x + a5.y,
                        s6 = a6.x + a6.y, s7 = a7.x + a7.y;

            // 16-lane reduce of 8 outputs: xor1 +sel, xor2 +sel, ror4 +sel, ror8.
            float t0, t1, t2, t3, t4, t5, t6, t7;
            DPPADD(t0, s0, 0xB1); DPPADD(t1, s1, 0xB1);
            DPPADD(t2, s2, 0xB1); DPPADD(t3, s3, 0xB1);
            DPPADD(t4, s4, 0xB1); DPPADD(t5, s5, 0xB1);
            DPPADD(t6, s6, 0xB1); DPPADD(t7, s7, 0xB1);
            const float p0 = (c & 1) ? t1 : t0;
            const float p1 = (c & 1) ? t3 : t2;
            const float p2 = (c & 1) ? t5 : t4;
            const float p3 = (c & 1) ? t7 : t6;
            float u0, u1, u2, u3;
            DPPADD(u0, p0, 0x4E); DPPADD(u1, p1, 0x4E);
            DPPADD(u2, p2, 0x4E); DPPADD(u3, p3, 0x4E);
            const float v0 = (c & 2) ? u1 : u0;
            const float v1 = (c & 2) ? u3 : u2;
            float q0, q1;
            DPPADD(q0, v0, 0x124); DPPADD(q1, v1, 0x124);
            float vfin = (c & 4) ? q1 : q0;
            DPPADD(vfin, vfin, 0x128);

            // Stage next xp chunk into the other LDS buffer (once per chunk;
            // rpf was loaded ~8 steps ago, so the vmcnt wait here is free).
            if (s == CH - 1 && ci != NCH - 1) {
                *(vf4*)&xchk[cb ^ 1][tid * 4] = rpf;
            }

            const float hn = fast_tanh(vfin + xpb);
            if (c < 8) {
                hbuf[1 - (s & 1)][haddr] = hn;        // h for next step
                ob[s * HH + jmine] = hn;              // output staging (LDS)
            }
            __syncthreads();
        }

        // ---- chunk boundary: flush outputs, prefetch chunk ci+2 ----
        // obuf[cb] is complete (post-barrier); next chunk writes obuf[cb^1],
        // so the flush read cannot race.
        const vf4 ov = *(const vf4*)&obuf[cb][tid * 4];
        *(vf4*)(obase + (size_t)ci * CH * HH + tid * 4) = ov;
        if (ci + 2 < NCH) {
            rpf = LD4(xbase + (size_t)(ci + 2) * CH * HH + tid * 4);
        }
        // These globals drain at the next chunk's first barrier — once per
        // 8 steps, overlapped with step-0 compute (~50 cyc/step amortized).
    }
}

extern "C" void kernel_launch(void* const* d_in, const int* in_sizes, int n_in,
                              void* d_out, int out_size, void* d_ws, size_t ws_size,
                              hipStream_t stream) {
    const float* x    = (const float*)d_in[0];
    const float* W_ih = (const float*)d_in[1];
    const float* W_hh = (const float*)d_in[2];
    const float* b_ih = (const float*)d_in[3];
    const float* b_hh = (const float*)d_in[4];
    float* out = (float*)d_out;

    const size_t xp_bytes = (size_t)BB * TT * HH * sizeof(float);   // 64 MiB
    // Aliased fallback stays correct: xp chunk k is loaded (2 chunks ahead)
    // strictly before out chunk k is flushed.
    float* xp = (ws_size >= xp_bytes) ? (float*)d_ws : out;

    xproj_kernel<<<dim3(512 * 2), dim3(256), 0, stream>>>(x, W_ih, b_ih, xp);
    rnn_kernel<<<dim3(BB), dim3(512), 0, stream>>>(W_hh, b_hh, xp, out);
}